// Round 4
// baseline (10990.618 us; speedup 1.0000x reference)
//
#include <hip/hip_runtime.h>

// PredictorRNN: 2076 sequential GRU steps in ONE persistent kernel.
// Round-14: FLAG-GATED PACKED EXCHANGE (replaces the tagged protocol).
// r13 falsified the poll-traffic model (16x less poll traffic => +0.6%).
// Remaining residual ~6000cy/step = the tagged protocol itself: every
// detect round is a full-payload MALL RTT + tag-verify VALU, and tags
// double the payload (16 tag bits per 16 data bits). New protocol:
//  - h stored PACKED (2 bf16 cols per u32, one shfl_xor in the epilogue):
//    payload 16KB/group/step (was 32KB), still relaxed agent (MALL).
//  - per-wave RELEASE FLAG: s_waitcnt vmcnt(0) then flag := s+1 (monotonic,
//    no re-zeroing). Consumer polls ONE 128B flag line (32 flags, 1 load +
//    s_sleep(1) per retry, no VALU sweep), then bulk-loads data exactly
//    once - unconditionally valid.
//  - distance-2 overwrite safety is inherited: a producer cannot reach
//    step s+1 stores while any group peer still stages h^(s-1), because
//    staging h^s requires that peer's step-s flag.
//  - flags: dedicated 4KB ws region. Fits: packing halves hbuf 1MiB->512KiB
//    so ws = 512K(hbuf)+512K(xext)+4K(flags) < old 1.5MiB footprint.
// xext (appended-x) exchange keeps the champion tagged scheme (28 uses).
// Signature the new path runs: WRITE_SIZE 1.08GB -> ~0.55GB, FETCH halves.
// 128 blocks x 256 threads (4 waves; weights register-resident).

typedef __attribute__((ext_vector_type(8))) short short8;   // 8 x bf16 frag
typedef __attribute__((ext_vector_type(4))) float floatx4;

#define B_    256
#define T_    256
#define I_    64
#define H_    512
#define HZ    8
#define LPAD  520            // LDS staging pitch (ushorts), rows 16B-aligned
#define HLSZ  (16 * LPAD)    // one staging buffer (16 rows)
#define HPAIR (H_ / 2)       // 256 u32 per packed h row
#define HSLAB (B_ * HPAIR)   // u32 per hbuf parity (65536 = 256KiB)

#define MFMA_BF16(acc, a, b) \
  acc = __builtin_amdgcn_mfma_f32_16x16x32_bf16((a), (b), (acc), 0, 0, 0)

// escalating backoff for the (rare, 28-step) tagged xext poll — champion tuning
#define POLL_BACKOFF(it)                         \
  do {                                           \
    if ((it) < 2)      __builtin_amdgcn_s_sleep(1);  \
    else if ((it) < 8) __builtin_amdgcn_s_sleep(4);  \
    else               __builtin_amdgcn_s_sleep(16); \
  } while (0)

__device__ __forceinline__ float bf2f(unsigned short u) {
  union { unsigned int i; float f; } v; v.i = ((unsigned int)u) << 16; return v.f;
}
__device__ __forceinline__ unsigned short f2bf(float f) {
  union { float f; unsigned int i; } v; v.f = f;
  return (unsigned short)((v.i + 0x7FFFu + ((v.i >> 16) & 1u)) >> 16);  // RNE
}
__device__ __forceinline__ short8 ld8_f32_to_bf16(const float* p) {
  short8 r;
#pragma unroll
  for (int e = 0; e < 8; ++e) r[e] = (short)f2bf(p[e]);
  return r;
}
__device__ __forceinline__ float sigm(float xx) {
  return __builtin_amdgcn_rcpf(1.f + __expf(-xx));
}
__device__ __forceinline__ float tanh_fast(float xx) {
  float e = __expf(2.f * xx);                 // +inf -> 1, 0 -> -1
  return 1.f - 2.f * __builtin_amdgcn_rcpf(e + 1.f);
}
// relaxed agent-scope atomics (lower to global ops with L1/L2 bypass -> MALL)
__device__ __forceinline__ unsigned long long ald64(const unsigned int* p) {
  return __hip_atomic_load((const unsigned long long*)p, __ATOMIC_RELAXED,
                           __HIP_MEMORY_SCOPE_AGENT);
}
__device__ __forceinline__ void ast32(unsigned int* p, unsigned int v) {
  __hip_atomic_store(p, v, __ATOMIC_RELAXED, __HIP_MEMORY_SCOPE_AGENT);
}

// ---- flag-gated packed h staging ----
// Poll the group's 32 per-wave flags (one 128B line; acquire so the
// subsequent data loads are ordered). Then load the 16KB packed slab once
// (8 x u64/thread, coalesced) and unpack to row-major LDS via ds_write_b64.
__device__ __forceinline__ void stage_h_flags(unsigned short* hl,
                                              const unsigned int* hb,
                                              const unsigned int* fl,
                                              unsigned int want,
                                              int tid, int lane) {
  unsigned int f = want;
  if (lane < 32)
    f = __hip_atomic_load(&fl[lane], __ATOMIC_ACQUIRE,
                          __HIP_MEMORY_SCOPE_AGENT);
  while (!__all((int)(f >= want))) {
    __builtin_amdgcn_s_sleep(1);
    if (lane < 32)
      f = __hip_atomic_load(&fl[lane], __ATOMIC_ACQUIRE,
                            __HIP_MEMORY_SCOPE_AGENT);
  }
  __builtin_amdgcn_sched_barrier(0);   // keep data loads below the poll
  unsigned long long v[8];
#pragma unroll
  for (int k = 0; k < 8; ++k)
    v[k] = ald64(hb + (((size_t)k * 256 + tid) << 1));
#pragma unroll
  for (int k = 0; k < 8; ++k) {
    const int r  = 2 * k + (tid >> 7);       // row 0..15
    const int cu = (2 * tid) & 255;          // u32 (col-pair) index in row
    *(unsigned long long*)&hl[r * LPAD + cu * 2] = v[k];
  }
}

extern "C" __global__ void __launch_bounds__(256, 1)
gru_chain(const float* __restrict__ x,       // [256][256][64] fp32
          const float* __restrict__ w_ih,    // [1536][64]   fp32
          const float* __restrict__ w_hh,    // [1536][512]  fp32
          const float* __restrict__ b_ih,    // [1536]       fp32
          const float* __restrict__ b_hh,    // [1536]       fp32
          const float* __restrict__ fc_w,    // [64][512]    fp32
          const float* __restrict__ fc_b,    // [64]         fp32
          float* __restrict__ out,           // [256][8][64] fp32
          unsigned int* __restrict__ hbuf,   // ws: [2][256][256] packed u32
          unsigned int* __restrict__ xext,   // ws: [8][256][64]  tagged u32
          unsigned int* __restrict__ flags)  // ws: [16][64] u32 (32 used/grp)
{
  const int tid  = threadIdx.x;
  const int wave = tid >> 6;                  // 0..3
  const int lane = tid & 63;
  const int bx   = blockIdx.x;                // 0..127
  const int grp  = bx & 15;                   // 16 groups x 8 blocks
  const int blk  = bx >> 4;                   // 0..7 block-in-group
  const int ju   = (blk << 2) | wave;         // 0..31 j-tile unit in group
  const int n16  = lane & 15;
  const int quad = lane >> 4;
  const int jg   = ju * 16 + n16;             // output column j (0..511)
  const int rowbase = grp * 16;               // 16 batch rows per group

  __shared__ __align__(16) unsigned short hls[2 * HLSZ];  // double-buffered

  unsigned int* gfl = flags + grp * 64;       // this group's flag line
  const int     fidx = blk * 4 + wave;        // this wave's flag slot

  // ---- one-time: fp32 weights -> bf16 B-fragments in registers ----
  // B-frag (16x16x32): lane holds B[k = kc*32 + quad*8 + e][n = lane&15];
  // B[k][j] = W[j][k] => weight row (gate*512+jg), cols kc*32+quad*8.
  short8 wR[18], wZ[18], wHN[16], wXN[2];
  {
    const int koff = quad * 8;
    const float* whr = w_hh + (size_t)(0 * H_ + jg) * H_ + koff;
    const float* whz = w_hh + (size_t)(1 * H_ + jg) * H_ + koff;
    const float* whn = w_hh + (size_t)(2 * H_ + jg) * H_ + koff;
#pragma unroll
    for (int kc = 0; kc < 16; ++kc) {
      wR[kc]  = ld8_f32_to_bf16(whr + kc * 32);
      wZ[kc]  = ld8_f32_to_bf16(whz + kc * 32);
      wHN[kc] = ld8_f32_to_bf16(whn + kc * 32);
    }
    const float* wir = w_ih + (size_t)(0 * H_ + jg) * I_ + koff;
    const float* wiz = w_ih + (size_t)(1 * H_ + jg) * I_ + koff;
    const float* win = w_ih + (size_t)(2 * H_ + jg) * I_ + koff;
#pragma unroll
    for (int kc = 0; kc < 2; ++kc) {
      wR[16 + kc] = ld8_f32_to_bf16(wir + kc * 32);
      wZ[16 + kc] = ld8_f32_to_bf16(wiz + kc * 32);
      wXN[kc]     = ld8_f32_to_bf16(win + kc * 32);
    }
  }
  const float brc = b_ih[jg]          + b_hh[jg];
  const float bzc = b_ih[H_ + jg]     + b_hh[H_ + jg];
  const float bxn = b_ih[2 * H_ + jg];
  const float bhn = b_hh[2 * H_ + jg];

  float hloc[4] = {0.f, 0.f, 0.f, 0.f};   // fp32 recurrent carry (C/D layout)

  int s = 0;
  for (int p = 0; p < HZ; ++p) {
    const int Tp = T_ + p;
    for (int t = 0; t < Tp; ++t) {
      // ---- x A-fragment (prefetch overlaps the flag poll) ----
      short8 xaf0, xaf1;
      if (t < T_) {
        const float* xs = x + ((size_t)(rowbase + n16) * T_ + t) * I_ + quad * 8;
        xaf0 = ld8_f32_to_bf16(xs);
        xaf1 = ld8_f32_to_bf16(xs + 32);
      }
      // ---- stage h^(s-1) into LDS[s&1] (flag-gated, packed) ----
      unsigned short* hl = &hls[(s & 1) * HLSZ];
      if (s > 0) {
        const unsigned int* hb = hbuf + (size_t)((s + 1) & 1) * HSLAB +
                                 (size_t)rowbase * HPAIR;
        stage_h_flags(hl, hb, gfl, (unsigned int)s, tid, lane);
      } else {  // s == 0: h_prev = 0
#pragma unroll
        for (int k = 0; k < 8; ++k) {
          const int r  = 2 * k + (tid >> 7);
          const int cu = (2 * tid) & 255;
          *(unsigned long long*)&hl[r * LPAD + cu * 2] = 0ull;
        }
      }
      // ---- xext A-fragment for appended timesteps (tagged, rare) ----
      if (t >= T_) {
        const int p2 = t - T_;
        const unsigned int wantx = (unsigned int)(p2 + 1);
        const unsigned int* xb =
            xext + ((size_t)p2 * B_ + rowbase + n16) * I_;
        unsigned long long u[8];
#pragma unroll
        for (int k = 0; k < 8; ++k) {
          int off = (k < 4) ? (quad * 8 + 2 * k) : (32 + quad * 8 + 2 * (k - 4));
          u[k] = ald64(xb + off);
        }
        int it = 0;
        for (;;) {
          bool all = true;
#pragma unroll
          for (int k = 0; k < 8; ++k) {
            unsigned int w0 = (unsigned int)u[k];
            unsigned int w1 = (unsigned int)(u[k] >> 32);
            if (((w0 >> 16) != wantx) || ((w1 >> 16) != wantx)) {
              all = false;
              int off = (k < 4) ? (quad * 8 + 2 * k)
                                : (32 + quad * 8 + 2 * (k - 4));
              u[k] = ald64(xb + off);
            }
          }
          if (all) break;
          POLL_BACKOFF(it);
          ++it;
        }
#pragma unroll
        for (int k = 0; k < 4; ++k) {
          xaf0[2 * k]     = (short)(unsigned short)u[k];
          xaf0[2 * k + 1] = (short)(unsigned short)(u[k] >> 32);
          xaf1[2 * k]     = (short)(unsigned short)u[4 + k];
          xaf1[2 * k + 1] = (short)(unsigned short)(u[4 + k] >> 32);
        }
      }
      __syncthreads();   // staging visible; also protects LDS parity reuse
      short8 haf[16];
#pragma unroll
      for (int kc = 0; kc < 16; ++kc)
        haf[kc] = *(const short8*)&hl[n16 * LPAD + kc * 32 + quad * 8];

      floatx4 aR = {0.f, 0.f, 0.f, 0.f};
      floatx4 aZ = {0.f, 0.f, 0.f, 0.f};
      floatx4 aN = {0.f, 0.f, 0.f, 0.f};
      floatx4 aX = {0.f, 0.f, 0.f, 0.f};
#pragma unroll
      for (int kc = 0; kc < 16; ++kc) {
        MFMA_BF16(aR, haf[kc], wR[kc]);
        MFMA_BF16(aZ, haf[kc], wZ[kc]);
        MFMA_BF16(aN, haf[kc], wHN[kc]);
      }
      MFMA_BF16(aR, xaf0, wR[16]);  MFMA_BF16(aR, xaf1, wR[17]);
      MFMA_BF16(aZ, xaf0, wZ[16]);  MFMA_BF16(aZ, xaf1, wZ[17]);
      MFMA_BF16(aX, xaf0, wXN[0]);  MFMA_BF16(aX, xaf1, wXN[1]);

      // ---- epilogue: packed col-pair stores + per-wave release flag ----
      unsigned int* hd = hbuf + (size_t)(s & 1) * HSLAB +
                         (size_t)rowbase * HPAIR;
      unsigned int bs[4];
#pragma unroll
      for (int i = 0; i < 4; ++i) {
        float rv = sigm(aR[i] + brc);
        float zv = sigm(aZ[i] + bzc);
        float nv = tanh_fast(aX[i] + bxn + rv * (aN[i] + bhn));
        float hn = (1.f - zv) * nv + zv * hloc[i];
        hloc[i]  = hn;
        bs[i]    = (unsigned int)f2bf(hn);
      }
      {
        // pack column pairs (jg even|odd) across lane pairs with one swap
        unsigned int p01 = bs[0] | (bs[1] << 16);
        unsigned int p23 = bs[2] | (bs[3] << 16);
        unsigned int q01 = __shfl_xor(p01, 1, 64);
        unsigned int q23 = __shfl_xor(p23, 1, 64);
        const int cp = ju * 8 + (n16 >> 1);   // col-pair index 0..255
        if ((n16 & 1) == 0) {                 // even col: low half, rows 0,1
          ast32(&hd[(size_t)(quad * 4 + 0) * HPAIR + cp],
                (p01 & 0xFFFFu) | (q01 << 16));
          ast32(&hd[(size_t)(quad * 4 + 1) * HPAIR + cp],
                (p01 >> 16) | (q01 & 0xFFFF0000u));
        } else {                              // odd col: high half, rows 2,3
          ast32(&hd[(size_t)(quad * 4 + 2) * HPAIR + cp],
                (q23 & 0xFFFFu) | (p23 << 16));
          ast32(&hd[(size_t)(quad * 4 + 3) * HPAIR + cp],
                (q23 >> 16) | (p23 & 0xFFFF0000u));
        }
        // release: all of this wave's data stores, then the flag
        asm volatile("s_waitcnt vmcnt(0)" ::: "memory");
        if (lane == 0) ast32(&gfl[fidx], (unsigned int)(s + 1));
      }
      ++s;
    }
    // ---- pass boundary: pred_p = h_final @ fc_w^T + fc_b ----
    {
      unsigned short* hl = &hls[(s & 1) * HLSZ];
      const unsigned int* hb = hbuf + (size_t)((s + 1) & 1) * HSLAB +
                               (size_t)rowbase * HPAIR;
      stage_h_flags(hl, hb, gfl, (unsigned int)s, tid, lane);
      __syncthreads();
      const int mm  = lane & 15;
      const int sub = lane >> 4;
#pragma unroll
      for (int cc = 0; cc < 2; ++cc) {
        const int c = ju * 2 + cc;
        const unsigned short* hrow = &hl[mm * LPAD + sub * 128];
        const float* wrow = fc_w + (size_t)c * H_ + sub * 128;
        float acc = 0.f;
#pragma unroll
        for (int kk = 0; kk < 128; kk += 8) {
          short8 hv = *(const short8*)(hrow + kk);
#pragma unroll
          for (int e = 0; e < 8; ++e)
            acc = fmaf(bf2f((unsigned short)hv[e]), wrow[kk + e], acc);
        }
        acc += __shfl_xor(acc, 16, 64);
        acc += __shfl_xor(acc, 32, 64);
        if (sub == 0) {
          float val = acc + fc_b[c];
          out[((size_t)(rowbase + mm) * HZ + p) * I_ + c] = val;   // fp32
          ast32(&xext[((size_t)p * B_ + rowbase + mm) * I_ + c],
                (((unsigned int)(p + 1)) << 16) | (unsigned int)f2bf(val));
        }
      }
      __syncthreads();   // fc reads done before next pass restages LDS[s&1]
    }
  }
}

extern "C" void kernel_launch(void* const* d_in, const int* in_sizes, int n_in,
                              void* d_out, int out_size, void* d_ws, size_t ws_size,
                              hipStream_t stream) {
  const float* x    = (const float*)d_in[0];
  const float* w_ih = (const float*)d_in[1];
  const float* w_hh = (const float*)d_in[2];
  const float* b_ih = (const float*)d_in[3];
  const float* b_hh = (const float*)d_in[4];
  const float* fc_w = (const float*)d_in[5];
  const float* fc_b = (const float*)d_in[6];
  float* out = (float*)d_out;

  unsigned char* ws = (unsigned char*)d_ws;
  const size_t hbuf_b  = (size_t)2 * HSLAB * 4;     // 512 KiB (packed bf16x2)
  const size_t xext_b  = (size_t)HZ * B_ * I_ * 4;  // 512 KiB (tagged u32)
  const size_t flags_b = (size_t)16 * 64 * 4;       // 4 KiB flag lines
  unsigned int* hbuf  = (unsigned int*)ws;
  unsigned int* xext  = (unsigned int*)(ws + hbuf_b);
  unsigned int* flags = (unsigned int*)(ws + hbuf_b + xext_b);

  // zero flags/tags (0 = invalid; harness 0xAA poison is also < any want).
  // Total 1028 KiB — WITHIN the champion's 1.5 MiB workspace footprint.
  hipMemsetAsync(d_ws, 0, hbuf_b + xext_b + flags_b, stream);

  // 128 blocks on 256 CUs — all co-resident (self-sync safe)
  gru_chain<<<dim3(128), dim3(256), 0, stream>>>(
      x, w_ih, w_hh, b_ih, b_hh, fc_w, fc_b, out, hbuf, xext, flags);
}

// Round 5
// 6173.609 us; speedup vs baseline: 1.7803x; 1.7803x over previous
//
#include <hip/hip_runtime.h>

// PredictorRNN: 2076 sequential GRU steps in ONE persistent kernel.
// Round-15 = round-10 champion (tagged "data is the signal" protocol —
// r14 PROVED flag-gating's extra serialized hops cost ~2 RTTs = +4.5ms,
// calibrating MALL RTT ~2600cy) + ADAPTIVE PRE-DELAY on the h sweep.
// Theory: the champion's speculative sweep samples MALL at ~T+1300cy,
// exactly when peer stores are arriving => marginal race => ~half the
// steps pay a full extra RTT + escalating sleep (detect ~T+5200 instead
// of ~T+3000). Fix: per-wave AIMD delay register (sleep dly*~128cy before
// the first sweep; first-sweep clean => dly-1, retry needed => dly+2,
// clamp [0,12]); retries use flat s_sleep(2) — no 1024cy escalation.
// Epilogue computes all 4 h values then issues the 4 stores back-to-back.
// Everything else identical to the champion: tagged u32 (step_tag<<16|bf16)
// via relaxed agent-scope atomics (MALL-coherent); consumers poll the data
// itself (detection == arrival); distance-2 overwrite safety by parity.
// 128 blocks x 256 threads (4 waves => 512-VGPR budget; weights stay
// register-resident — 512-thread blocks cap at 256 VGPR and SPILL: round-9).

typedef __attribute__((ext_vector_type(8))) short short8;   // 8 x bf16 frag
typedef __attribute__((ext_vector_type(4))) float floatx4;

#define B_    256
#define T_    256
#define I_    64
#define H_    512
#define HZ    8
#define LPAD  520            // LDS staging pitch (ushorts), rows 16B-aligned
#define HLSZ  (16 * LPAD)    // one staging buffer (16 rows)

#define MFMA_BF16(acc, a, b) \
  acc = __builtin_amdgcn_mfma_f32_16x16x32_bf16((a), (b), (acc), 0, 0, 0)

// escalating backoff for the (rare, 28-step) tagged xext poll — champion tuning
#define POLL_BACKOFF(it)                         \
  do {                                           \
    if ((it) < 2)      __builtin_amdgcn_s_sleep(1);  \
    else if ((it) < 8) __builtin_amdgcn_s_sleep(4);  \
    else               __builtin_amdgcn_s_sleep(16); \
  } while (0)

__device__ __forceinline__ float bf2f(unsigned short u) {
  union { unsigned int i; float f; } v; v.i = ((unsigned int)u) << 16; return v.f;
}
__device__ __forceinline__ unsigned short f2bf(float f) {
  union { float f; unsigned int i; } v; v.f = f;
  return (unsigned short)((v.i + 0x7FFFu + ((v.i >> 16) & 1u)) >> 16);  // RNE
}
__device__ __forceinline__ short8 ld8_f32_to_bf16(const float* p) {
  short8 r;
#pragma unroll
  for (int e = 0; e < 8; ++e) r[e] = (short)f2bf(p[e]);
  return r;
}
__device__ __forceinline__ float sigm(float xx) {
  return __builtin_amdgcn_rcpf(1.f + __expf(-xx));
}
__device__ __forceinline__ float tanh_fast(float xx) {
  float e = __expf(2.f * xx);                 // +inf -> 1, 0 -> -1
  return 1.f - 2.f * __builtin_amdgcn_rcpf(e + 1.f);
}
// relaxed agent-scope atomics (lower to global ops with L1/L2 bypass -> MALL)
__device__ __forceinline__ unsigned long long ald64(const unsigned int* p) {
  return __hip_atomic_load((const unsigned long long*)p, __ATOMIC_RELAXED,
                           __HIP_MEMORY_SCOPE_AGENT);
}
__device__ __forceinline__ void ast32(unsigned int* p, unsigned int v) {
  __hip_atomic_store(p, v, __ATOMIC_RELAXED, __HIP_MEMORY_SCOPE_AGENT);
}

// ---- tagged h staging with ADAPTIVE PRE-DELAY ----
// thread's slice: row i (i=0..15), 8B at word offset 2*tid within the row.
// Sleep dly quanta (~128cy each) so peer stores are visible when the first
// sweep samples the MALL; AIMD-tune dly from first-sweep success. Retries
// (rare once tuned) reload only stale words with flat s_sleep(2).
__device__ __forceinline__ void stage_h16(unsigned short* hl,
                                          const unsigned int* hb,
                                          unsigned int want, int tid,
                                          int& dly) {
  for (int i = 0; i < dly; ++i) __builtin_amdgcn_s_sleep(2);
  unsigned long long v[16];
#pragma unroll
  for (int i = 0; i < 16; ++i)
    v[i] = ald64(hb + (size_t)i * H_ + 2 * tid);
  bool fail1 = false;
  int it = 0;
  for (;;) {
    bool all = true;
#pragma unroll
    for (int i = 0; i < 16; ++i) {
      unsigned int w0 = (unsigned int)v[i];
      unsigned int w1 = (unsigned int)(v[i] >> 32);
      if (((w0 >> 16) != want) || ((w1 >> 16) != want)) all = false;
    }
    if (all) break;
    if (it == 0) fail1 = true;
    __builtin_amdgcn_s_sleep(2);
#pragma unroll
    for (int i = 0; i < 16; ++i) {
      unsigned int w0 = (unsigned int)v[i];
      unsigned int w1 = (unsigned int)(v[i] >> 32);
      if (((w0 >> 16) != want) || ((w1 >> 16) != want))
        v[i] = ald64(hb + (size_t)i * H_ + 2 * tid);
    }
    ++it;
  }
  // AIMD update (wave-uniform): converge to the visibility latency
  if (__any((int)fail1)) { if (dly < 12) dly += 2; }
  else                   { if (dly > 0)  dly -= 1; }
#pragma unroll
  for (int i = 0; i < 16; ++i) {
    unsigned int w0 = (unsigned int)v[i];
    unsigned int w1 = (unsigned int)(v[i] >> 32);
    *(unsigned int*)&hl[i * LPAD + 2 * tid] = (w0 & 0xffffu) | (w1 << 16);
  }
}

extern "C" __global__ void __launch_bounds__(256, 1)
gru_chain(const float* __restrict__ x,       // [256][256][64] fp32
          const float* __restrict__ w_ih,    // [1536][64]   fp32
          const float* __restrict__ w_hh,    // [1536][512]  fp32
          const float* __restrict__ b_ih,    // [1536]       fp32
          const float* __restrict__ b_hh,    // [1536]       fp32
          const float* __restrict__ fc_w,    // [64][512]    fp32
          const float* __restrict__ fc_b,    // [64]         fp32
          float* __restrict__ out,           // [256][8][64] fp32
          unsigned int* __restrict__ hbuf,   // ws: [2][256][512] tagged u32
          unsigned int* __restrict__ xext)   // ws: [8][256][64]  tagged u32
{
  const int tid  = threadIdx.x;
  const int wave = tid >> 6;                  // 0..3
  const int lane = tid & 63;
  const int bx   = blockIdx.x;                // 0..127
  const int grp  = bx & 15;                   // 16 groups x 8 blocks
  const int ju   = ((bx >> 4) << 2) | wave;   // 0..31 j-tile unit in group
  const int n16  = lane & 15;
  const int quad = lane >> 4;
  const int jg   = ju * 16 + n16;             // output column j (0..511)
  const int rowbase = grp * 16;               // 16 batch rows per group

  __shared__ __align__(16) unsigned short hls[2 * HLSZ];  // double-buffered

  // ---- one-time: fp32 weights -> bf16 B-fragments in registers ----
  // B-frag (16x16x32): lane holds B[k = kc*32 + quad*8 + e][n = lane&15];
  // B[k][j] = W[j][k] => weight row (gate*512+jg), cols kc*32+quad*8.
  short8 wR[18], wZ[18], wHN[16], wXN[2];
  {
    const int koff = quad * 8;
    const float* whr = w_hh + (size_t)(0 * H_ + jg) * H_ + koff;
    const float* whz = w_hh + (size_t)(1 * H_ + jg) * H_ + koff;
    const float* whn = w_hh + (size_t)(2 * H_ + jg) * H_ + koff;
#pragma unroll
    for (int kc = 0; kc < 16; ++kc) {
      wR[kc]  = ld8_f32_to_bf16(whr + kc * 32);
      wZ[kc]  = ld8_f32_to_bf16(whz + kc * 32);
      wHN[kc] = ld8_f32_to_bf16(whn + kc * 32);
    }
    const float* wir = w_ih + (size_t)(0 * H_ + jg) * I_ + koff;
    const float* wiz = w_ih + (size_t)(1 * H_ + jg) * I_ + koff;
    const float* win = w_ih + (size_t)(2 * H_ + jg) * I_ + koff;
#pragma unroll
    for (int kc = 0; kc < 2; ++kc) {
      wR[16 + kc] = ld8_f32_to_bf16(wir + kc * 32);
      wZ[16 + kc] = ld8_f32_to_bf16(wiz + kc * 32);
      wXN[kc]     = ld8_f32_to_bf16(win + kc * 32);
    }
  }
  const float brc = b_ih[jg]          + b_hh[jg];
  const float bzc = b_ih[H_ + jg]     + b_hh[H_ + jg];
  const float bxn = b_ih[2 * H_ + jg];
  const float bhn = b_hh[2 * H_ + jg];

  float hloc[4] = {0.f, 0.f, 0.f, 0.f};   // fp32 recurrent carry (C/D layout)
  int   dly = 4;                           // adaptive pre-delay (sleep quanta)

  int s = 0;
  for (int p = 0; p < HZ; ++p) {
    const int Tp = T_ + p;
    for (int t = 0; t < Tp; ++t) {
      // ---- x A-fragment (prefetch overlaps the h pre-delay + sweep) ----
      short8 xaf0, xaf1;
      if (t < T_) {
        const float* xs = x + ((size_t)(rowbase + n16) * T_ + t) * I_ + quad * 8;
        xaf0 = ld8_f32_to_bf16(xs);
        xaf1 = ld8_f32_to_bf16(xs + 32);
      }
      // ---- stage h^(s-1) (tagged, self-synchronizing) into LDS[s&1] ----
      unsigned short* hl = &hls[(s & 1) * HLSZ];
      if (s > 0) {
        const unsigned int* hb = hbuf + (size_t)((s + 1) & 1) * (B_ * H_) +
                                 (size_t)rowbase * H_;
        stage_h16(hl, hb, (unsigned int)s, tid, dly);
      } else {  // s == 0: h_prev = 0
#pragma unroll
        for (int i = 0; i < 16; ++i)
          *(unsigned int*)&hl[i * LPAD + 2 * tid] = 0u;
      }
      // ---- xext A-fragment for appended timesteps (tagged, rare) ----
      if (t >= T_) {
        const int p2 = t - T_;
        const unsigned int wantx = (unsigned int)(p2 + 1);
        const unsigned int* xb =
            xext + ((size_t)p2 * B_ + rowbase + n16) * I_;
        unsigned long long u[8];
#pragma unroll
        for (int k = 0; k < 8; ++k) {
          int off = (k < 4) ? (quad * 8 + 2 * k) : (32 + quad * 8 + 2 * (k - 4));
          u[k] = ald64(xb + off);
        }
        int it = 0;
        for (;;) {
          bool all = true;
#pragma unroll
          for (int k = 0; k < 8; ++k) {
            unsigned int w0 = (unsigned int)u[k];
            unsigned int w1 = (unsigned int)(u[k] >> 32);
            if (((w0 >> 16) != wantx) || ((w1 >> 16) != wantx)) {
              all = false;
              int off = (k < 4) ? (quad * 8 + 2 * k)
                                : (32 + quad * 8 + 2 * (k - 4));
              u[k] = ald64(xb + off);
            }
          }
          if (all) break;
          POLL_BACKOFF(it);
          ++it;
        }
#pragma unroll
        for (int k = 0; k < 4; ++k) {
          xaf0[2 * k]     = (short)(unsigned short)u[k];
          xaf0[2 * k + 1] = (short)(unsigned short)(u[k] >> 32);
          xaf1[2 * k]     = (short)(unsigned short)u[4 + k];
          xaf1[2 * k + 1] = (short)(unsigned short)(u[4 + k] >> 32);
        }
      }
      __syncthreads();   // staging visible; also protects LDS parity reuse
      short8 haf[16];
#pragma unroll
      for (int kc = 0; kc < 16; ++kc)
        haf[kc] = *(const short8*)&hl[n16 * LPAD + kc * 32 + quad * 8];

      floatx4 aR = {0.f, 0.f, 0.f, 0.f};
      floatx4 aZ = {0.f, 0.f, 0.f, 0.f};
      floatx4 aN = {0.f, 0.f, 0.f, 0.f};
      floatx4 aX = {0.f, 0.f, 0.f, 0.f};
#pragma unroll
      for (int kc = 0; kc < 16; ++kc) {
        MFMA_BF16(aR, haf[kc], wR[kc]);
        MFMA_BF16(aZ, haf[kc], wZ[kc]);
        MFMA_BF16(aN, haf[kc], wHN[kc]);
      }
      MFMA_BF16(aR, xaf0, wR[16]);  MFMA_BF16(aR, xaf1, wR[17]);
      MFMA_BF16(aZ, xaf0, wZ[16]);  MFMA_BF16(aZ, xaf1, wZ[17]);
      MFMA_BF16(aX, xaf0, wXN[0]);  MFMA_BF16(aX, xaf1, wXN[1]);

      // ---- epilogue: compute all 4 h values, then stores back-to-back ----
      // (earlier last-store issue => earlier MALL visibility for peers)
      unsigned int* hd = hbuf + (size_t)(s & 1) * (B_ * H_);
      const unsigned int tg = ((unsigned int)(s + 1)) << 16;
      unsigned int hv[4];
#pragma unroll
      for (int i = 0; i < 4; ++i) {
        float rv = sigm(aR[i] + brc);
        float zv = sigm(aZ[i] + bzc);
        float nv = tanh_fast(aX[i] + bxn + rv * (aN[i] + bhn));
        float hn = (1.f - zv) * nv + zv * hloc[i];
        hloc[i]  = hn;
        hv[i]    = tg | (unsigned int)f2bf(hn);
      }
#pragma unroll
      for (int i = 0; i < 4; ++i)
        ast32(&hd[(size_t)(rowbase + quad * 4 + i) * H_ + jg], hv[i]);
      ++s;
    }
    // ---- pass boundary: pred_p = h_final @ fc_w^T + fc_b ----
    {
      unsigned short* hl = &hls[(s & 1) * HLSZ];
      const unsigned int* hb = hbuf + (size_t)((s + 1) & 1) * (B_ * H_) +
                               (size_t)rowbase * H_;
      stage_h16(hl, hb, (unsigned int)s, tid, dly);
      __syncthreads();
      const int mm  = lane & 15;
      const int sub = lane >> 4;
#pragma unroll
      for (int cc = 0; cc < 2; ++cc) {
        const int c = ju * 2 + cc;
        const unsigned short* hrow = &hl[mm * LPAD + sub * 128];
        const float* wrow = fc_w + (size_t)c * H_ + sub * 128;
        float acc = 0.f;
#pragma unroll
        for (int kk = 0; kk < 128; kk += 8) {
          short8 hv2 = *(const short8*)(hrow + kk);
#pragma unroll
          for (int e = 0; e < 8; ++e)
            acc = fmaf(bf2f((unsigned short)hv2[e]), wrow[kk + e], acc);
        }
        acc += __shfl_xor(acc, 16, 64);
        acc += __shfl_xor(acc, 32, 64);
        if (sub == 0) {
          float val = acc + fc_b[c];
          out[((size_t)(rowbase + mm) * HZ + p) * I_ + c] = val;   // fp32
          ast32(&xext[((size_t)p * B_ + rowbase + mm) * I_ + c],
                (((unsigned int)(p + 1)) << 16) | (unsigned int)f2bf(val));
        }
      }
      __syncthreads();   // fc reads done before next pass restages LDS[s&1]
    }
  }
}

extern "C" void kernel_launch(void* const* d_in, const int* in_sizes, int n_in,
                              void* d_out, int out_size, void* d_ws, size_t ws_size,
                              hipStream_t stream) {
  const float* x    = (const float*)d_in[0];
  const float* w_ih = (const float*)d_in[1];
  const float* w_hh = (const float*)d_in[2];
  const float* b_ih = (const float*)d_in[3];
  const float* b_hh = (const float*)d_in[4];
  const float* fc_w = (const float*)d_in[5];
  const float* fc_b = (const float*)d_in[6];
  float* out = (float*)d_out;

  unsigned char* ws = (unsigned char*)d_ws;
  const size_t hbuf_b = (size_t)2 * B_ * H_ * 4;   // 1 MiB (tagged u32)
  const size_t xext_b = (size_t)HZ * B_ * I_ * 4;  // 512 KiB (tagged u32)
  unsigned int* hbuf = (unsigned int*)ws;
  unsigned int* xext = (unsigned int*)(ws + hbuf_b);

  // zero tags (0 = invalid; the harness's 0xAA poison is also invalid)
  hipMemsetAsync(d_ws, 0, hbuf_b + xext_b, stream);

  // 128 blocks on 256 CUs — all co-resident (self-sync safe)
  gru_chain<<<dim3(128), dim3(256), 0, stream>>>(
      x, w_ih, w_hh, b_ih, b_hh, fc_w, fc_b, out, hbuf, xext);
}